// Round 2
// baseline (1043.867 us; speedup 1.0000x reference)
//
#include <hip/hip_runtime.h>
#include <math.h>

// Problem: x(128,512,1024) f32, weight(512,512,64,2) f32, t_emb unused.
// y = irfft64( einsum(rfft64(x)[:,:, :64], w) ); out = y>0 ? 2y : 1.2y
// Factored as 3 GEMM phases (no FFT): A = truncated rDFT, B = per-freq
// complex mixing, C = truncated irDFT + fused LeakyReLU-add epilogue.

// ws layout (float offsets)
constexpr size_t FT_OFF = 0;                        // [1024][128]  fwd DFT table
constexpr size_t GT_OFF = 131072;                   // [128][1024]  inv DFT table
constexpr size_t X2_OFF = 262144;                   // [64][65536][2] freq-major spectrum
constexpr size_t Y2_OFF = X2_OFF + 8388608;         // [64][65536][2]
constexpr size_t W2_OFF = Y2_OFF + 8388608;         // [64][262144][2] freq-major weight
constexpr size_t WS_FULL_FLOATS = W2_OFF + 33554432;

__global__ __launch_bounds__(256) void init_tables(float* __restrict__ FT,
                                                   float* __restrict__ GT) {
    int idx = blockIdx.x * 256 + threadIdx.x;      // 65536 = 1024 m * 64 k
    int m = idx >> 6, k = idx & 63;
    int t = (k * m) & 1023;
    float ang = (float)((double)t * (6.283185307179586 / 1024.0));
    float s, c;
    sincosf(ang, &s, &c);
    // rfft: X[k] = sum x[m] (cos - i sin)
    FT[m * 128 + 2 * k]     = c;
    FT[m * 128 + 2 * k + 1] = -s;
    // irfft (modes<Nyq): y[m] = a0*Yr[0] + sum_k ak*(Yr cos - Yi sin), a0=1/N, ak=2/N
    float a = (k == 0 ? 1.0f : 2.0f) * (1.0f / 1024.0f);
    GT[(2 * k) * 1024 + m]     = a * c;
    GT[(2 * k + 1) * 1024 + m] = -a * s;
}

// weight (262144 dc-rows x 64 k) of float2 -> W2 (64 k x 262144 dc) of float2
__global__ __launch_bounds__(256) void wtrans(const float2* __restrict__ W,
                                              float2* __restrict__ W2) {
    __shared__ float2 t[32][33];
    int dc0 = blockIdx.x * 32;
    int k0  = blockIdx.y * 32;
    int c = threadIdx.x & 31, rr = threadIdx.x >> 5;
#pragma unroll
    for (int p = 0; p < 4; ++p) {
        int r = rr + p * 8;
        t[r][c] = W[(size_t)(dc0 + r) * 64 + k0 + c];
    }
    __syncthreads();
#pragma unroll
    for (int p = 0; p < 4; ++p) {
        int kk = rr + p * 8;
        W2[(size_t)(k0 + kk) * 262144 + dc0 + c] = t[c][kk];
    }
}

// Phase A: X2[k][R][ri] = sum_m x[R][m] * FT[m][2k+ri],  R=(b,c) row; 65536x1024 * 1024x128
__global__ __launch_bounds__(256) void dft_fwd(const float* __restrict__ x,
                                               const float* __restrict__ FT,
                                               float* __restrict__ X2) {
    __shared__ float As[16][128];
    __shared__ float Bs[16][128];
    const int tid = threadIdx.x;
    const int tx = tid & 15, ty = tid >> 4;
    const size_t R0 = (size_t)blockIdx.x * 128;
    float acc[8][8] = {};
    for (int k0 = 0; k0 < 1024; k0 += 16) {
        {
            int r = tid >> 2, q = tid & 3;           // r: 0..63, two passes -> 128 rows
#pragma unroll
            for (int p = 0; p < 2; ++p) {
                int rr = r + p * 64;
                float4 v = *(const float4*)(x + (R0 + rr) * 1024 + k0 + q * 4);
                As[q * 4 + 0][rr] = v.x;
                As[q * 4 + 1][rr] = v.y;
                As[q * 4 + 2][rr] = v.z;
                As[q * 4 + 3][rr] = v.w;
            }
        }
        {
            int row = tid >> 5, q = tid & 31;
            *(float4*)&Bs[row][q * 4]     = *(const float4*)(FT + (size_t)(k0 + row) * 128 + q * 4);
            *(float4*)&Bs[row + 8][q * 4] = *(const float4*)(FT + (size_t)(k0 + row + 8) * 128 + q * 4);
        }
        __syncthreads();
#pragma unroll
        for (int kk = 0; kk < 16; ++kk) {
            float4 a0 = *(float4*)&As[kk][ty * 4];
            float4 a1 = *(float4*)&As[kk][64 + ty * 4];
            float4 b0 = *(float4*)&Bs[kk][tx * 4];
            float4 b1 = *(float4*)&Bs[kk][64 + tx * 4];
            float a[8] = {a0.x, a0.y, a0.z, a0.w, a1.x, a1.y, a1.z, a1.w};
            float b[8] = {b0.x, b0.y, b0.z, b0.w, b1.x, b1.y, b1.z, b1.w};
#pragma unroll
            for (int i = 0; i < 8; ++i)
#pragma unroll
                for (int j = 0; j < 8; ++j) acc[i][j] = fmaf(a[i], b[j], acc[i][j]);
        }
        __syncthreads();
    }
    // rows: i<4 -> ty*4+i ; i>=4 -> 64+ty*4+(i-4)
    // cols: j pair (2j,2j+1) of {tx*4.. , 64+tx*4..} -> freqs {tx*2, tx*2+1, 32+tx*2, 32+tx*2+1}
#pragma unroll
    for (int i = 0; i < 8; ++i) {
        size_t R = R0 + (i < 4 ? ty * 4 + i : 64 + ty * 4 + (i - 4));
#pragma unroll
        for (int jh = 0; jh < 2; ++jh)
#pragma unroll
            for (int jj = 0; jj < 2; ++jj) {
                int kf = jh * 32 + tx * 2 + jj;
                float2 v = make_float2(acc[i][jh * 4 + jj * 2], acc[i][jh * 4 + jj * 2 + 1]);
                *(float2*)(X2 + (size_t)kf * 131072 + R * 2) = v;
            }
    }
}

// Phase B: per-k complex GEMM  Y[b,d] = sum_c X[b,c]*W[d,c]
template <bool USEW2>
__global__ __launch_bounds__(256) void specmul(const float* __restrict__ X2,
                                               const float* __restrict__ W,
                                               float* __restrict__ Y2) {
    __shared__ float Xs[64][68];
    __shared__ float Ws[64][68];
    const int tid = threadIdx.x;
    const int txd = tid & 15, tyb = tid >> 4;
    const int k = blockIdx.z;
    const int d0 = blockIdx.x * 64, b0 = blockIdx.y * 64;
    const float* Xk = X2 + (size_t)k * 131072;
    float accr[4][4] = {}, acci[4][4] = {};
    for (int c0 = 0; c0 < 512; c0 += 32) {
        {
            int q = tid & 15;
#pragma unroll
            for (int p = 0; p < 4; ++p) {
                int bb = (tid >> 4) + p * 16;
                *(float4*)&Xs[bb][q * 4] =
                    *(const float4*)(Xk + ((size_t)(b0 + bb) * 512 + c0) * 2 + q * 4);
            }
        }
        if (USEW2) {
            const float* Wk = W + (size_t)k * 524288;
            int q = tid & 15;
#pragma unroll
            for (int p = 0; p < 4; ++p) {
                int dd = (tid >> 4) + p * 16;
                *(float4*)&Ws[dd][q * 4] =
                    *(const float4*)(Wk + ((size_t)(d0 + dd) * 512 + c0) * 2 + q * 4);
            }
        } else {
            int cc = tid & 31;
#pragma unroll
            for (int p = 0; p < 8; ++p) {
                int dd = (tid >> 5) + p * 8;
                float2 v = *(const float2*)(W + ((size_t)(d0 + dd) * 512 + (c0 + cc)) * 128 + k * 2);
                Ws[dd][cc * 2]     = v.x;
                Ws[dd][cc * 2 + 1] = v.y;
            }
        }
        __syncthreads();
#pragma unroll
        for (int cc = 0; cc < 32; ++cc) {
            float xr[4], xi[4], wr[4], wi[4];
#pragma unroll
            for (int i = 0; i < 4; ++i) {
                float2 v = *(float2*)&Xs[tyb * 4 + i][cc * 2];
                xr[i] = v.x; xi[i] = v.y;
            }
            // d cols: {txd*2, txd*2+1, 32+txd*2, 32+txd*2+1}
#pragma unroll
            for (int j = 0; j < 4; ++j) {
                int dd = (j >> 1) * 32 + txd * 2 + (j & 1);
                float2 v = *(float2*)&Ws[dd][cc * 2];
                wr[j] = v.x; wi[j] = v.y;
            }
#pragma unroll
            for (int i = 0; i < 4; ++i)
#pragma unroll
                for (int j = 0; j < 4; ++j) {
                    accr[i][j] = fmaf(xr[i], wr[j], fmaf(-xi[i], wi[j], accr[i][j]));
                    acci[i][j] = fmaf(xr[i], wi[j], fmaf(xi[i], wr[j], acci[i][j]));
                }
        }
        __syncthreads();
    }
    float* Yk = Y2 + (size_t)k * 131072;
#pragma unroll
    for (int i = 0; i < 4; ++i) {
        int b = b0 + tyb * 4 + i;
#pragma unroll
        for (int jh = 0; jh < 2; ++jh) {
            int d = d0 + jh * 32 + txd * 2;
            float4 v = make_float4(accr[i][jh * 2], acci[i][jh * 2],
                                   accr[i][jh * 2 + 1], acci[i][jh * 2 + 1]);
            *(float4*)(Yk + ((size_t)b * 512 + d) * 2) = v;
        }
    }
}

// Phase C: out[R][m] = f( sum_kcol Y[R][kcol] * GT[kcol][m] ), f(y)=y + (y>0?y:0.2y)
__global__ __launch_bounds__(256) void idft_leaky(const float* __restrict__ Y2,
                                                  const float* __restrict__ GT,
                                                  float* __restrict__ out) {
    __shared__ float As[16][128];
    __shared__ float Bs[16][128];
    const int tid = threadIdx.x;
    const int tx = tid & 15, ty = tid >> 4;
    const size_t R0 = (size_t)blockIdx.x * 128;
    const int m0 = blockIdx.y * 128;
    float acc[8][8] = {};
    for (int k0 = 0; k0 < 128; k0 += 16) {
        {
            int kk = tid >> 5, q = tid & 31;
            const float* src = Y2 + (size_t)(k0 / 2 + kk) * 131072 + R0 * 2;
            float4 v1 = *(const float4*)(src + q * 4);
            float4 v2 = *(const float4*)(src + 128 + q * 4);
            As[2 * kk][2 * q]         = v1.x;
            As[2 * kk + 1][2 * q]     = v1.y;
            As[2 * kk][2 * q + 1]     = v1.z;
            As[2 * kk + 1][2 * q + 1] = v1.w;
            As[2 * kk][64 + 2 * q]         = v2.x;
            As[2 * kk + 1][64 + 2 * q]     = v2.y;
            As[2 * kk][65 + 2 * q]         = v2.z;
            As[2 * kk + 1][65 + 2 * q]     = v2.w;
        }
        {
            int row = tid >> 5, q = tid & 31;
            *(float4*)&Bs[row][q * 4]     = *(const float4*)(GT + (size_t)(k0 + row) * 1024 + m0 + q * 4);
            *(float4*)&Bs[row + 8][q * 4] = *(const float4*)(GT + (size_t)(k0 + row + 8) * 1024 + m0 + q * 4);
        }
        __syncthreads();
#pragma unroll
        for (int kk = 0; kk < 16; ++kk) {
            float4 a0 = *(float4*)&As[kk][ty * 4];
            float4 a1 = *(float4*)&As[kk][64 + ty * 4];
            float4 b0 = *(float4*)&Bs[kk][tx * 4];
            float4 b1 = *(float4*)&Bs[kk][64 + tx * 4];
            float a[8] = {a0.x, a0.y, a0.z, a0.w, a1.x, a1.y, a1.z, a1.w};
            float b[8] = {b0.x, b0.y, b0.z, b0.w, b1.x, b1.y, b1.z, b1.w};
#pragma unroll
            for (int i = 0; i < 8; ++i)
#pragma unroll
                for (int j = 0; j < 8; ++j) acc[i][j] = fmaf(a[i], b[j], acc[i][j]);
        }
        __syncthreads();
    }
#pragma unroll
    for (int i = 0; i < 8; ++i) {
        size_t R = R0 + (i < 4 ? ty * 4 + i : 64 + ty * 4 + (i - 4));
        float* dst = out + R * 1024 + m0;
#pragma unroll
        for (int jh = 0; jh < 2; ++jh) {
            float y0 = acc[i][jh * 4 + 0];
            float y1 = acc[i][jh * 4 + 1];
            float y2 = acc[i][jh * 4 + 2];
            float y3 = acc[i][jh * 4 + 3];
            float4 v;
            v.x = y0 > 0.0f ? 2.0f * y0 : 1.2f * y0;
            v.y = y1 > 0.0f ? 2.0f * y1 : 1.2f * y1;
            v.z = y2 > 0.0f ? 2.0f * y2 : 1.2f * y2;
            v.w = y3 > 0.0f ? 2.0f * y3 : 1.2f * y3;
            *(float4*)(dst + jh * 64 + tx * 4) = v;
        }
    }
}

extern "C" void kernel_launch(void* const* d_in, const int* in_sizes, int n_in,
                              void* d_out, int out_size, void* d_ws, size_t ws_size,
                              hipStream_t stream) {
    const float* x = (const float*)d_in[0];   // (128,512,1024)
    const float* w = (const float*)d_in[2];   // (512,512,64,2); d_in[1] (t_emb) unused
    float* out = (float*)d_out;
    float* ws  = (float*)d_ws;

    float* FT = ws + FT_OFF;
    float* GT = ws + GT_OFF;
    float* X2 = ws + X2_OFF;
    float* Y2 = ws + Y2_OFF;
    float* W2 = ws + W2_OFF;
    const bool usew2 = ws_size >= WS_FULL_FLOATS * sizeof(float);

    init_tables<<<256, 256, 0, stream>>>(FT, GT);
    if (usew2) wtrans<<<dim3(8192, 2), 256, 0, stream>>>((const float2*)w, (float2*)W2);
    dft_fwd<<<512, 256, 0, stream>>>(x, FT, X2);
    if (usew2) specmul<true><<<dim3(8, 2, 64), 256, 0, stream>>>(X2, W2, Y2);
    else       specmul<false><<<dim3(8, 2, 64), 256, 0, stream>>>(X2, w, Y2);
    idft_leaky<<<dim3(512, 8), 256, 0, stream>>>(Y2, GT, out);
}